// Round 1
// baseline (1411.919 us; speedup 1.0000x reference)
//
#include <hip/hip_runtime.h>
#include <cmath>

#define B64 64
#define H 1024
#define E 512
#define DG 64
#define GIN 2624   // E + 2H + DG
#define TZ 128
#define TU 256
#define V 8000
#define VT 8128    // V + TZ
#define NC 16128   // V + VT

using bf16x8 = __attribute__((ext_vector_type(8))) short;
using f32x4  = __attribute__((ext_vector_type(4))) float;

__device__ inline unsigned short f2bf(float f) {
    unsigned u = __float_as_uint(f);
    u += 0x7fffu + ((u >> 16) & 1u);   // RNE
    return (unsigned short)(u >> 16);
}

// ---------------------------------------------------------------------------
// Fused: out[row] += sum_col tanh( (A @ W[:,koff:koff+K].T)[row,col]
//                                  + addv[b,col] ) * multv[b,col]
// A: (M,1024) row-major (row = t*64 + b). W rows n: W[n*ldw + koff + k].
// grid = (M/128, 1024/128), block 256.  bf16 MFMA 16x16x32, fp32 accum.
// ---------------------------------------------------------------------------
__global__ __launch_bounds__(256) void fused_tanh_dot(
    const float* __restrict__ A,
    const float* __restrict__ W, int ldw, int koff,
    const float* __restrict__ addv, int add_stride,
    const float* __restrict__ multv, int mult_stride,
    float* __restrict__ outs)
{
    __shared__ short As[128][40];
    __shared__ short Bs[128][40];
    const int tid  = threadIdx.x;
    const int wave = tid >> 6, lane = tid & 63;
    const int wm = wave >> 1, wn = wave & 1;
    const int q = lane >> 4, l16 = lane & 15;
    const int m0 = blockIdx.x * 128;
    const int n0 = blockIdx.y * 128;

    f32x4 acc[4][4];
#pragma unroll
    for (int i = 0; i < 4; ++i)
#pragma unroll
        for (int j = 0; j < 4; ++j) acc[i][j] = f32x4{0.f, 0.f, 0.f, 0.f};

    for (int kt = 0; kt < 32; ++kt) {
        const int k0 = kt * 32;
        __syncthreads();
#pragma unroll
        for (int i = 0; i < 4; ++i) {
            int slot = i * 256 + tid;
            int row  = slot >> 3;
            int kq   = (slot & 7) << 2;
            float4 a = *(const float4*)(A + (size_t)(m0 + row) * 1024 + k0 + kq);
            short4 pa; pa.x = f2bf(a.x); pa.y = f2bf(a.y); pa.z = f2bf(a.z); pa.w = f2bf(a.w);
            *(short4*)&As[row][kq] = pa;
            float4 w = *(const float4*)(W + (size_t)(n0 + row) * ldw + koff + k0 + kq);
            short4 pw; pw.x = f2bf(w.x); pw.y = f2bf(w.y); pw.z = f2bf(w.z); pw.w = f2bf(w.w);
            *(short4*)&Bs[row][kq] = pw;
        }
        __syncthreads();
        bf16x8 af[4], bfr[4];
#pragma unroll
        for (int t = 0; t < 4; ++t) af[t]  = *(bf16x8*)&As[wm * 64 + t * 16 + l16][q * 8];
#pragma unroll
        for (int t = 0; t < 4; ++t) bfr[t] = *(bf16x8*)&Bs[wn * 64 + t * 16 + l16][q * 8];
#pragma unroll
        for (int tm = 0; tm < 4; ++tm)
#pragma unroll
            for (int tn = 0; tn < 4; ++tn)
                acc[tm][tn] = __builtin_amdgcn_mfma_f32_16x16x32_bf16(
                    af[tm], bfr[tn], acc[tm][tn], 0, 0, 0);
    }

    // epilogue: C row = m0 + wm*64 + tm*16 + q*4 + r ; col = n0 + wn*64 + tn*16 + l16
#pragma unroll
    for (int tm = 0; tm < 4; ++tm) {
#pragma unroll
        for (int r = 0; r < 4; ++r) {
            int R = m0 + wm * 64 + tm * 16 + q * 4 + r;
            int b = R & 63;
            float s = 0.f;
#pragma unroll
            for (int tn = 0; tn < 4; ++tn) {
                int col = n0 + wn * 64 + tn * 16 + l16;
                float e = acc[tm][tn][r] + addv[(size_t)b * add_stride + col];
                s += tanhf(e) * multv[(size_t)b * mult_stride + col];
            }
            s += __shfl_xor(s, 1);
            s += __shfl_xor(s, 2);
            s += __shfl_xor(s, 4);
            s += __shfl_xor(s, 8);
            if (l16 == 0) atomicAdd(&outs[R], s);
        }
    }
}

// ---------------------------------------------------------------------------
// Generic small fp32 GEMM: C(64,N) = A(64,K) @ W(N, >=K)^T + bias
// grid.x = N/64, block 256, 64x64 tile, 4x4 micro-tile.
// ---------------------------------------------------------------------------
__global__ __launch_bounds__(256) void gemm_bt_f32(
    const float* __restrict__ A, int K,
    const float* __restrict__ W, int ldw, int koff,
    const float* __restrict__ bias,
    float* __restrict__ C, int N)
{
    __shared__ float As[64][36];
    __shared__ float Ws[64][36];
    const int tid = threadIdx.x;
    const int n0  = blockIdx.x * 64;
    const int tx = tid & 15, ty = tid >> 4;
    float acc[4][4] = {};

    for (int k0 = 0; k0 < K; k0 += 32) {
        __syncthreads();
#pragma unroll
        for (int i = 0; i < 2; ++i) {
            int slot = i * 256 + tid;
            int row  = slot >> 3;
            int kq   = (slot & 7) << 2;
            *(float4*)&As[row][kq] = *(const float4*)(A + (size_t)row * K + k0 + kq);
            *(float4*)&Ws[row][kq] = *(const float4*)(W + (size_t)(n0 + row) * ldw + koff + k0 + kq);
        }
        __syncthreads();
#pragma unroll 8
        for (int kk = 0; kk < 32; ++kk) {
            float a[4], w[4];
#pragma unroll
            for (int i = 0; i < 4; ++i) a[i] = As[ty * 4 + i][kk];
#pragma unroll
            for (int j = 0; j < 4; ++j) w[j] = Ws[tx * 4 + j][kk];
#pragma unroll
            for (int i = 0; i < 4; ++i)
#pragma unroll
                for (int j = 0; j < 4; ++j) acc[i][j] += a[i] * w[j];
        }
    }
#pragma unroll
    for (int i = 0; i < 4; ++i) {
        int b = ty * 4 + i;
#pragma unroll
        for (int j = 0; j < 4; ++j) {
            int n = n0 + tx * 4 + j;
            C[(size_t)b * N + n] = acc[i][j] + bias[n];
        }
    }
}

// x[b] = [ emb_W[mt[b]] (512) | u_ctx (1024) | z_ctx (1024) | degree (64) ]
__global__ void k_gather(const int* __restrict__ mt, const float* __restrict__ embW,
                         const float* __restrict__ degree, float* __restrict__ x)
{
    int b = blockIdx.x, tid = threadIdx.x;   // block 128
    int m = mt[b];
    for (int k = tid; k < E; k += 128) x[(size_t)b * GIN + k] = embW[(size_t)m * E + k];
    if (tid < DG) x[(size_t)b * GIN + E + 2 * H + tid] = degree[b * DG + tid];
}

// softmax over t of scores[t*64+b], then ctx[b,h] = sum_t alpha[t]*enc[t,b,h]
// writes ctx into x[b*GIN+xoff+h] and y[b*3072+yoff+h]. grid (64,4), block 256.
__global__ __launch_bounds__(256) void k_softmax_ctx(
    const float* __restrict__ scores, const float* __restrict__ enc, int T,
    float* __restrict__ x, int xoff, float* __restrict__ y, int yoff)
{
    __shared__ float red[256];
    __shared__ float al[256];
    int b = blockIdx.x, hc = blockIdx.y, tid = threadIdx.x;
    float s = (tid < T) ? scores[tid * B64 + b] : -1e30f;
    red[tid] = s; __syncthreads();
    for (int off = 128; off > 0; off >>= 1) {
        if (tid < off) red[tid] = fmaxf(red[tid], red[tid + off]);
        __syncthreads();
    }
    float mx = red[0]; __syncthreads();
    float e = (tid < T) ? expf(s - mx) : 0.f;
    red[tid] = e; __syncthreads();
    for (int off = 128; off > 0; off >>= 1) {
        if (tid < off) red[tid] += red[tid + off];
        __syncthreads();
    }
    float inv = 1.f / red[0];
    al[tid] = e * inv;
    __syncthreads();
    int h = hc * 256 + tid;
    float acc = 0.f;
    for (int t = 0; t < T; ++t) acc += al[t] * enc[((size_t)t * B64 + b) * H + h];
    x[(size_t)b * GIN + xoff + h] = acc;
    y[(size_t)b * 3072 + yoff + h] = acc;
}

__global__ void k_gate(const float* __restrict__ gi, const float* __restrict__ gh,
                       const float* __restrict__ h0, float* __restrict__ gru,
                       float* __restrict__ y, float* __restrict__ out_hid,
                       float* __restrict__ out_gru)
{
    int b = blockIdx.x, tid = threadIdx.x;
    for (int j = tid; j < H; j += 256) {
        float ir = gi[(size_t)b * 3072 + j];
        float iz = gi[(size_t)b * 3072 + H + j];
        float in_ = gi[(size_t)b * 3072 + 2 * H + j];
        float hr = gh[(size_t)b * 3072 + j];
        float hz = gh[(size_t)b * 3072 + H + j];
        float hn = gh[(size_t)b * 3072 + 2 * H + j];
        float r = 1.f / (1.f + expf(-(ir + hr)));
        float z = 1.f / (1.f + expf(-(iz + hz)));
        float n = tanhf(in_ + r * hn);
        float h = h0[(size_t)b * H + j];
        float o = (1.f - z) * n + z * h;
        gru[(size_t)b * H + j] = o;
        y[(size_t)b * 3072 + 2 * H + j] = o;
        out_hid[(size_t)b * H + j] = o;
        out_gru[(size_t)b * H + j] = o;
    }
}

// m[b] = max_t z_cs[t*64+b]; ew[b,t] = exp(z_cs - m). grid 64, block 128.
__global__ void k_expw(const float* __restrict__ z_cs, float* __restrict__ ew,
                       float* __restrict__ mb)
{
    __shared__ float red[128];
    int b = blockIdx.x, t = threadIdx.x;
    float s = z_cs[t * B64 + b];
    red[t] = s; __syncthreads();
    for (int off = 64; off > 0; off >>= 1) {
        if (t < off) red[t] = fmaxf(red[t], red[t + off]);
        __syncthreads();
    }
    float m = red[0];
    ew[b * TZ + t] = expf(s - m);
    if (t == 0) mb[b] = m;
}

// zcopy[b,v] = log( sum_t ew[b,t]*sz[b,t,v] ) + mb[b]. grid (8,64), block 256.
__global__ __launch_bounds__(256) void k_sparse(
    const float* __restrict__ sz, const float* __restrict__ ew,
    const float* __restrict__ mb, float* __restrict__ zcopy)
{
    __shared__ float es[TZ];
    int c = blockIdx.x, b = blockIdx.y, tid = threadIdx.x;
    if (tid < TZ) es[tid] = ew[b * TZ + tid];
    __syncthreads();
    if (tid >= 254) return;
    int v4 = c * 254 + tid;               // 8 * 254 = 2032 = 8128/4, exact cover
    const float4* base = (const float4*)(sz + (size_t)b * TZ * VT);
    float4 acc = make_float4(0.f, 0.f, 0.f, 0.f);
    for (int t = 0; t < TZ; ++t) {
        float4 xv = base[(size_t)t * (VT / 4) + v4];
        float e = es[t];
        acc.x += e * xv.x; acc.y += e * xv.y; acc.z += e * xv.z; acc.w += e * xv.w;
    }
    float m = mb[b];
    int v = v4 * 4;
    zcopy[(size_t)b * VT + v + 0] = logf(acc.x) + m;
    zcopy[(size_t)b * VT + v + 1] = logf(acc.y) + m;
    zcopy[(size_t)b * VT + v + 2] = logf(acc.z) + m;
    zcopy[(size_t)b * VT + v + 3] = logf(acc.w) + m;
}

// final softmax over [gen(8000) | zcopy(8128)]; proba combine. grid 64, block 256.
__global__ __launch_bounds__(256) void k_final(
    const float* __restrict__ gen, const float* __restrict__ zcopy,
    float* __restrict__ proba)
{
    __shared__ float lg[NC];
    __shared__ float wred[8];
    int b = blockIdx.x, tid = threadIdx.x;
    int lane = tid & 63, wave = tid >> 6;
    for (int i = tid; i < V; i += 256) lg[i] = gen[(size_t)b * V + i];
    for (int i = tid; i < VT; i += 256) lg[V + i] = zcopy[(size_t)b * VT + i];
    __syncthreads();
    float mx = -1e30f;
    for (int i = tid; i < NC; i += 256) mx = fmaxf(mx, lg[i]);
#pragma unroll
    for (int off = 32; off > 0; off >>= 1) mx = fmaxf(mx, __shfl_xor(mx, off));
    if (lane == 0) wred[wave] = mx;
    __syncthreads();
    mx = fmaxf(fmaxf(wred[0], wred[1]), fmaxf(wred[2], wred[3]));
    __syncthreads();
    float sm = 0.f;
    for (int i = tid; i < NC; i += 256) sm += expf(lg[i] - mx);
#pragma unroll
    for (int off = 32; off > 0; off >>= 1) sm += __shfl_xor(sm, off);
    if (lane == 0) wred[wave] = sm;
    __syncthreads();
    float invZ = 1.f / (wred[0] + wred[1] + wred[2] + wred[3]);
    for (int v = tid; v < VT; v += 256) {
        float p = expf(lg[V + v] - mx) * invZ;
        if (v < V) p += expf(lg[v] - mx) * invZ;
        proba[(size_t)b * VT + v] = p;
    }
}

extern "C" void kernel_launch(void* const* d_in, const int* in_sizes, int n_in,
                              void* d_out, int out_size, void* d_ws, size_t ws_size,
                              hipStream_t stream)
{
    const float* z_enc  = (const float*)d_in[0];
    const float* u_enc  = (const float*)d_in[1];
    const int*   mt     = (const int*)d_in[2];
    const float* degree = (const float*)d_in[3];
    const float* h0     = (const float*)d_in[4];
    const float* sz     = (const float*)d_in[5];
    const float* embW   = (const float*)d_in[6];
    const float* azW    = (const float*)d_in[7];
    const float* azb    = (const float*)d_in[8];
    const float* azv    = (const float*)d_in[9];
    const float* auW    = (const float*)d_in[10];
    const float* aub    = (const float*)d_in[11];
    const float* auv    = (const float*)d_in[12];
    const float* Wih    = (const float*)d_in[13];
    const float* Whh    = (const float*)d_in[14];
    const float* bih    = (const float*)d_in[15];
    const float* bhh    = (const float*)d_in[16];
    const float* pW     = (const float*)d_in[17];
    const float* pb     = (const float*)d_in[18];
    const float* c2W    = (const float*)d_in[19];
    const float* c2b    = (const float*)d_in[20];

    float* ws       = (float*)d_ws;
    float* scores_z = ws;              // 8192   (t*64+b)
    float* scores_u = ws + 8192;       // 16384
    float* z_cs     = ws + 24576;      // 8192
    float* hbz      = ws + 32768;      // 65536
    float* hbu      = ws + 98304;      // 65536
    float* x        = ws + 163840;     // 64*2624
    float* y        = ws + 331776;     // 64*3072
    float* gi       = ws + 528384;     // 64*3072
    float* gh       = ws + 724992;     // 64*3072
    float* gru      = ws + 921600;     // 64*1024
    float* ew       = ws + 987136;     // 64*128
    float* mb       = ws + 995328;     // 64
    float* gen      = ws + 995392;     // 64*8000
    float* zcopy    = ws + 1507392;    // 64*8128

    float* out_proba = (float*)d_out;
    float* out_hid   = out_proba + (size_t)B64 * VT;
    float* out_gru   = out_hid + (size_t)B64 * H;

    // zero atomic accumulators (scores_z | scores_u | z_cs are contiguous)
    hipMemsetAsync(scores_z, 0, 32768 * sizeof(float), stream);

    // hb[b,h] = hidden @ W[:, :H]^T + bias   (per-batch half of attn energy)
    gemm_bt_f32<<<16, 256, 0, stream>>>(h0, 1024, azW, 2048, 0, azb, hbz, 1024);
    gemm_bt_f32<<<16, 256, 0, stream>>>(h0, 1024, auW, 2048, 0, aub, hbu, 1024);
    k_gather<<<64, 128, 0, stream>>>(mt, embW, degree, x);
    gemm_bt_f32<<<48, 256, 0, stream>>>(h0, 1024, Whh, 1024, 0, bhh, gh, 3072);

    // attn energies (bf16 MFMA) fused with tanh·v reduction -> scores
    fused_tanh_dot<<<dim3(64, 8), 256, 0, stream>>>(z_enc, azW, 2048, 1024,
                                                    hbz, 1024, azv, 0, scores_z);
    fused_tanh_dot<<<dim3(128, 8), 256, 0, stream>>>(u_enc, auW, 2048, 1024,
                                                     hbu, 1024, auv, 0, scores_u);

    // softmax over t + ctx; ctx written into GRU input x and proj input y
    k_softmax_ctx<<<dim3(64, 4), 256, 0, stream>>>(scores_z, z_enc, TZ, x, 1536, y, 0);
    k_softmax_ctx<<<dim3(64, 4), 256, 0, stream>>>(scores_u, u_enc, TU, x, 512, y, 1024);

    // GRU
    gemm_bt_f32<<<48, 256, 0, stream>>>(x, GIN, Wih, GIN, 0, bih, gi, 3072);
    k_gate<<<64, 256, 0, stream>>>(gi, gh, h0, gru, y, out_hid, out_gru);

    // copy2: tanh(z_enc @ c2W^T + c2b) · gru  ->  z_cs   (bf16 MFMA fused)
    fused_tanh_dot<<<dim3(64, 8), 256, 0, stream>>>(z_enc, c2W, 1024, 0,
                                                    c2b, 0, gru, 1024, z_cs);

    // gen_score = [z_ctx|u_ctx|gru] @ proj_W^T + proj_b
    gemm_bt_f32<<<125, 256, 0, stream>>>(y, 3072, pW, 3072, 0, pb, gen, 8000);

    // sparse log-sum-exp path
    k_expw<<<64, 128, 0, stream>>>(z_cs, ew, mb);
    k_sparse<<<dim3(8, 64), 256, 0, stream>>>(sz, ew, mb, zcopy);

    // final softmax + combine
    k_final<<<64, 256, 0, stream>>>(gen, zcopy, out_proba);
}

// Round 2
// 921.113 us; speedup vs baseline: 1.5328x; 1.5328x over previous
//
#include <hip/hip_runtime.h>
#include <cmath>

#define B64 64
#define H 1024
#define E 512
#define DG 64
#define GIN 2624   // E + 2H + DG
#define TZ 128
#define TU 256
#define V 8000
#define VT 8128    // V + TZ
#define NC 16128   // V + VT

using bf16x8 = __attribute__((ext_vector_type(8))) short;
using f32x4  = __attribute__((ext_vector_type(4))) float;

// pack two fp32 -> two bf16 in one dword (round-half-up via +0x8000, then v_perm)
__device__ inline unsigned pack2(float a, float b) {
    unsigned ua = __float_as_uint(a) + 0x8000u;
    unsigned ub = __float_as_uint(b) + 0x8000u;
    return __builtin_amdgcn_perm(ub, ua, 0x07060302u);  // lo16=hi(a), hi16=hi(b)
}
__device__ inline uint2 pack4(float4 v) {
    return make_uint2(pack2(v.x, v.y), pack2(v.z, v.w));
}

// ---------------------------------------------------------------------------
// Fused: out[row] += sum_col tanh( (A @ W[:,koff:+1024].T)[row,col]
//                                  + addv[b,col] ) * multv[b,col]
// A: (M,1024) row-major (row = t*64 + b). grid (M/128, 1024/128), block 256.
// ---------------------------------------------------------------------------
__global__ __launch_bounds__(256) void fused_tanh_dot(
    const float* __restrict__ A,
    const float* __restrict__ W, int ldw, int koff,
    const float* __restrict__ addv, int add_stride,
    const float* __restrict__ multv, int mult_stride,
    float* __restrict__ outs)
{
    __shared__ short As[128][40];
    __shared__ short Bs[128][40];
    const int tid  = threadIdx.x;
    const int wave = tid >> 6, lane = tid & 63;
    const int wm = wave >> 1, wn = wave & 1;
    const int q = lane >> 4, l16 = lane & 15;
    const int m0 = blockIdx.x * 128;
    const int n0 = blockIdx.y * 128;

    f32x4 acc[4][4];
#pragma unroll
    for (int i = 0; i < 4; ++i)
#pragma unroll
        for (int j = 0; j < 4; ++j) acc[i][j] = f32x4{0.f, 0.f, 0.f, 0.f};

    for (int kt = 0; kt < 32; ++kt) {
        const int k0 = kt * 32;
        __syncthreads();
#pragma unroll
        for (int i = 0; i < 4; ++i) {
            int slot = i * 256 + tid;
            int row  = slot >> 3;
            int kq   = (slot & 7) << 2;
            float4 a = *(const float4*)(A + (size_t)(m0 + row) * 1024 + k0 + kq);
            *(uint2*)&As[row][kq] = pack4(a);
            float4 w = *(const float4*)(W + (size_t)(n0 + row) * ldw + koff + k0 + kq);
            *(uint2*)&Bs[row][kq] = pack4(w);
        }
        __syncthreads();
        bf16x8 af[4], bfr[4];
#pragma unroll
        for (int t = 0; t < 4; ++t) af[t]  = *(bf16x8*)&As[wm * 64 + t * 16 + l16][q * 8];
#pragma unroll
        for (int t = 0; t < 4; ++t) bfr[t] = *(bf16x8*)&Bs[wn * 64 + t * 16 + l16][q * 8];
#pragma unroll
        for (int tm = 0; tm < 4; ++tm)
#pragma unroll
            for (int tn = 0; tn < 4; ++tn)
                acc[tm][tn] = __builtin_amdgcn_mfma_f32_16x16x32_bf16(
                    af[tm], bfr[tn], acc[tm][tn], 0, 0, 0);
    }

    // C row = m0 + wm*64 + tm*16 + q*4 + r ; col = n0 + wn*64 + tn*16 + l16
#pragma unroll
    for (int tm = 0; tm < 4; ++tm) {
#pragma unroll
        for (int r = 0; r < 4; ++r) {
            int R = m0 + wm * 64 + tm * 16 + q * 4 + r;
            int b = R & 63;
            float s = 0.f;
#pragma unroll
            for (int tn = 0; tn < 4; ++tn) {
                int col = n0 + wn * 64 + tn * 16 + l16;
                float e = acc[tm][tn][r] + addv[(size_t)b * add_stride + col];
                s += tanhf(e) * multv[(size_t)b * mult_stride + col];
            }
            s += __shfl_xor(s, 1);
            s += __shfl_xor(s, 2);
            s += __shfl_xor(s, 4);
            s += __shfl_xor(s, 8);
            if (l16 == 0) atomicAdd(&outs[R], s);
        }
    }
}

// ---------------------------------------------------------------------------
// C(64,N) += A(64,lda chunk) @ W(N,ldw)^T  via bf16 MFMA, K-split over grid.y.
// C must be zeroed. bias added by chunk 0. grid (N/64, nchunks), block 256.
// ---------------------------------------------------------------------------
__global__ __launch_bounds__(256) void gemm_bt_mfma(
    const float* __restrict__ A, int lda,
    const float* __restrict__ W, int ldw, int koff,
    const float* __restrict__ bias,
    float* __restrict__ C, int N,
    int ks_total, int ks_chunk)
{
    __shared__ short As[64][40];
    __shared__ short Bs[64][40];
    const int tid  = threadIdx.x;
    const int wave = tid >> 6, lane = tid & 63;
    const int wm = wave >> 1, wn = wave & 1;
    const int q = lane >> 4, l16 = lane & 15;
    const int n0 = blockIdx.x * 64;
    const int kb = blockIdx.y * ks_chunk;
    const int ke = min(kb + ks_chunk, ks_total);

    f32x4 acc[2][2];
#pragma unroll
    for (int i = 0; i < 2; ++i)
#pragma unroll
        for (int j = 0; j < 2; ++j) acc[i][j] = f32x4{0.f, 0.f, 0.f, 0.f};

    for (int ks = kb; ks < ke; ++ks) {
        const int k0 = ks * 32;
        __syncthreads();
#pragma unroll
        for (int i = 0; i < 2; ++i) {
            int slot = i * 256 + tid;
            int row  = slot >> 3;
            int kq   = (slot & 7) << 2;
            float4 a = *(const float4*)(A + (size_t)row * lda + k0 + kq);
            *(uint2*)&As[row][kq] = pack4(a);
            float4 w = *(const float4*)(W + (size_t)(n0 + row) * ldw + koff + k0 + kq);
            *(uint2*)&Bs[row][kq] = pack4(w);
        }
        __syncthreads();
        bf16x8 af[2], bfr[2];
#pragma unroll
        for (int t = 0; t < 2; ++t) af[t]  = *(bf16x8*)&As[wm * 32 + t * 16 + l16][q * 8];
#pragma unroll
        for (int t = 0; t < 2; ++t) bfr[t] = *(bf16x8*)&Bs[wn * 32 + t * 16 + l16][q * 8];
#pragma unroll
        for (int tm = 0; tm < 2; ++tm)
#pragma unroll
            for (int tn = 0; tn < 2; ++tn)
                acc[tm][tn] = __builtin_amdgcn_mfma_f32_16x16x32_bf16(
                    af[tm], bfr[tn], acc[tm][tn], 0, 0, 0);
    }

#pragma unroll
    for (int tm = 0; tm < 2; ++tm) {
#pragma unroll
        for (int r = 0; r < 4; ++r) {
            int b = wm * 32 + tm * 16 + q * 4 + r;
#pragma unroll
            for (int tn = 0; tn < 2; ++tn) {
                int n = n0 + wn * 32 + tn * 16 + l16;
                float v = acc[tm][tn][r];
                if (blockIdx.y == 0) v += bias[n];
                atomicAdd(&C[(size_t)b * N + n], v);
            }
        }
    }
}

// x[b] = [ emb_W[mt[b]] (512) | u_ctx (1024) | z_ctx (1024) | degree (64) ]
__global__ void k_gather(const int* __restrict__ mt, const float* __restrict__ embW,
                         const float* __restrict__ degree, float* __restrict__ x)
{
    int b = blockIdx.x, tid = threadIdx.x;   // block 128
    int m = mt[b];
    for (int k = tid; k < E; k += 128) x[(size_t)b * GIN + k] = embW[(size_t)m * E + k];
    if (tid < DG) x[(size_t)b * GIN + E + 2 * H + tid] = degree[b * DG + tid];
}

// softmax over t of scores[t*64+b], then ctx[b,h] = sum_t alpha[t]*enc[t,b,h]
__global__ __launch_bounds__(256) void k_softmax_ctx(
    const float* __restrict__ scores, const float* __restrict__ enc, int T,
    float* __restrict__ x, int xoff, float* __restrict__ y, int yoff)
{
    __shared__ float red[256];
    __shared__ float al[256];
    int b = blockIdx.x, hc = blockIdx.y, tid = threadIdx.x;
    float s = (tid < T) ? scores[tid * B64 + b] : -1e30f;
    red[tid] = s; __syncthreads();
    for (int off = 128; off > 0; off >>= 1) {
        if (tid < off) red[tid] = fmaxf(red[tid], red[tid + off]);
        __syncthreads();
    }
    float mx = red[0]; __syncthreads();
    float e = (tid < T) ? expf(s - mx) : 0.f;
    red[tid] = e; __syncthreads();
    for (int off = 128; off > 0; off >>= 1) {
        if (tid < off) red[tid] += red[tid + off];
        __syncthreads();
    }
    float inv = 1.f / red[0];
    al[tid] = e * inv;
    __syncthreads();
    int h = hc * 256 + tid;
    float acc = 0.f;
    for (int t = 0; t < T; ++t) acc += al[t] * enc[((size_t)t * B64 + b) * H + h];
    x[(size_t)b * GIN + xoff + h] = acc;
    y[(size_t)b * 3072 + yoff + h] = acc;
}

__global__ void k_gate(const float* __restrict__ gi, const float* __restrict__ gh,
                       const float* __restrict__ h0, float* __restrict__ gru,
                       float* __restrict__ y, float* __restrict__ out_hid,
                       float* __restrict__ out_gru)
{
    int b = blockIdx.x, tid = threadIdx.x;
    for (int j = tid; j < H; j += 256) {
        float ir = gi[(size_t)b * 3072 + j];
        float iz = gi[(size_t)b * 3072 + H + j];
        float in_ = gi[(size_t)b * 3072 + 2 * H + j];
        float hr = gh[(size_t)b * 3072 + j];
        float hz = gh[(size_t)b * 3072 + H + j];
        float hn = gh[(size_t)b * 3072 + 2 * H + j];
        float r = 1.f / (1.f + expf(-(ir + hr)));
        float z = 1.f / (1.f + expf(-(iz + hz)));
        float n = tanhf(in_ + r * hn);
        float h = h0[(size_t)b * H + j];
        float o = (1.f - z) * n + z * h;
        gru[(size_t)b * H + j] = o;
        y[(size_t)b * 3072 + 2 * H + j] = o;
        out_hid[(size_t)b * H + j] = o;
        out_gru[(size_t)b * H + j] = o;
    }
}

// m[b] = max_t z_cs[t*64+b]; ew[b,t] = exp(z_cs - m). grid 64, block 128.
__global__ void k_expw(const float* __restrict__ z_cs, float* __restrict__ ew,
                       float* __restrict__ mb)
{
    __shared__ float red[128];
    int b = blockIdx.x, t = threadIdx.x;
    float s = z_cs[t * B64 + b];
    red[t] = s; __syncthreads();
    for (int off = 64; off > 0; off >>= 1) {
        if (t < off) red[t] = fmaxf(red[t], red[t + off]);
        __syncthreads();
    }
    float m = red[0];
    ew[b * TZ + t] = expf(s - m);
    if (t == 0) mb[b] = m;
}

// zcopy[b,v] = log( sum_t ew[b,t]*sz[b,t,v] ) + mb[b]. grid (8,64), block 256.
__global__ __launch_bounds__(256) void k_sparse(
    const float* __restrict__ sz, const float* __restrict__ ew,
    const float* __restrict__ mb, float* __restrict__ zcopy)
{
    __shared__ float es[TZ];
    int c = blockIdx.x, b = blockIdx.y, tid = threadIdx.x;
    if (tid < TZ) es[tid] = ew[b * TZ + tid];
    __syncthreads();
    if (tid >= 254) return;
    int v4 = c * 254 + tid;               // 8 * 254 = 2032 = 8128/4, exact cover
    const float4* base = (const float4*)(sz + (size_t)b * TZ * VT);
    float4 acc = make_float4(0.f, 0.f, 0.f, 0.f);
    for (int t = 0; t < TZ; ++t) {
        float4 xv = base[(size_t)t * (VT / 4) + v4];
        float e = es[t];
        acc.x += e * xv.x; acc.y += e * xv.y; acc.z += e * xv.z; acc.w += e * xv.w;
    }
    float m = mb[b];
    int v = v4 * 4;
    zcopy[(size_t)b * VT + v + 0] = logf(acc.x) + m;
    zcopy[(size_t)b * VT + v + 1] = logf(acc.y) + m;
    zcopy[(size_t)b * VT + v + 2] = logf(acc.z) + m;
    zcopy[(size_t)b * VT + v + 3] = logf(acc.w) + m;
}

// final softmax over [gen(8000) | zcopy(8128)]; proba combine. grid 64, block 256.
__global__ __launch_bounds__(256) void k_final(
    const float* __restrict__ gen, const float* __restrict__ zcopy,
    float* __restrict__ proba)
{
    __shared__ float lg[NC];
    __shared__ float wred[8];
    int b = blockIdx.x, tid = threadIdx.x;
    int lane = tid & 63, wave = tid >> 6;
    for (int i = tid; i < V; i += 256) lg[i] = gen[(size_t)b * V + i];
    for (int i = tid; i < VT; i += 256) lg[V + i] = zcopy[(size_t)b * VT + i];
    __syncthreads();
    float mx = -1e30f;
    for (int i = tid; i < NC; i += 256) mx = fmaxf(mx, lg[i]);
#pragma unroll
    for (int off = 32; off > 0; off >>= 1) mx = fmaxf(mx, __shfl_xor(mx, off));
    if (lane == 0) wred[wave] = mx;
    __syncthreads();
    mx = fmaxf(fmaxf(wred[0], wred[1]), fmaxf(wred[2], wred[3]));
    __syncthreads();
    float sm = 0.f;
    for (int i = tid; i < NC; i += 256) sm += expf(lg[i] - mx);
#pragma unroll
    for (int off = 32; off > 0; off >>= 1) sm += __shfl_xor(sm, off);
    if (lane == 0) wred[wave] = sm;
    __syncthreads();
    float invZ = 1.f / (wred[0] + wred[1] + wred[2] + wred[3]);
    for (int v = tid; v < VT; v += 256) {
        float p = expf(lg[V + v] - mx) * invZ;
        if (v < V) p += expf(lg[v] - mx) * invZ;
        proba[(size_t)b * VT + v] = p;
    }
}

extern "C" void kernel_launch(void* const* d_in, const int* in_sizes, int n_in,
                              void* d_out, int out_size, void* d_ws, size_t ws_size,
                              hipStream_t stream)
{
    const float* z_enc  = (const float*)d_in[0];
    const float* u_enc  = (const float*)d_in[1];
    const int*   mt     = (const int*)d_in[2];
    const float* degree = (const float*)d_in[3];
    const float* h0     = (const float*)d_in[4];
    const float* sz     = (const float*)d_in[5];
    const float* embW   = (const float*)d_in[6];
    const float* azW    = (const float*)d_in[7];
    const float* azb    = (const float*)d_in[8];
    const float* azv    = (const float*)d_in[9];
    const float* auW    = (const float*)d_in[10];
    const float* aub    = (const float*)d_in[11];
    const float* auv    = (const float*)d_in[12];
    const float* Wih    = (const float*)d_in[13];
    const float* Whh    = (const float*)d_in[14];
    const float* bih    = (const float*)d_in[15];
    const float* bhh    = (const float*)d_in[16];
    const float* pW     = (const float*)d_in[17];
    const float* pb     = (const float*)d_in[18];
    const float* c2W    = (const float*)d_in[19];
    const float* c2b    = (const float*)d_in[20];

    float* ws       = (float*)d_ws;
    // zeroed region (atomic accumulators), contiguous:
    float* scores_z = ws;               // 8192   (t*64+b)
    float* scores_u = ws + 8192;        // 16384
    float* z_cs     = ws + 24576;       // 8192
    float* hbz      = ws + 32768;       // 65536
    float* hbu      = ws + 98304;       // 65536
    float* gi       = ws + 163840;      // 196608 (64*3072)
    float* gh       = ws + 360448;      // 196608
    float* gen      = ws + 557056;      // 512000 (64*8000)
    // non-zeroed:
    float* x        = ws + 1069056;     // 64*2624
    float* y        = ws + 1236992;     // 64*3072
    float* gru      = ws + 1433600;     // 64*1024
    float* ew       = ws + 1499136;     // 64*128
    float* mb       = ws + 1507328;     // 64
    float* zcopy    = ws + 1507392;     // 64*8128

    float* out_proba = (float*)d_out;
    float* out_hid   = out_proba + (size_t)B64 * VT;
    float* out_gru   = out_hid + (size_t)B64 * H;

    // zero all atomic accumulators in one shot (1,069,056 floats)
    hipMemsetAsync(ws, 0, 1069056 * sizeof(float), stream);

    // hb[b,h] = hidden @ W[:, :H]^T + bias (per-batch half of attn energy)
    gemm_bt_mfma<<<dim3(16, 4), 256, 0, stream>>>(h0, 1024, azW, 2048, 0, azb, hbz, 1024, 32, 8);
    gemm_bt_mfma<<<dim3(16, 4), 256, 0, stream>>>(h0, 1024, auW, 2048, 0, aub, hbu, 1024, 32, 8);
    k_gather<<<64, 128, 0, stream>>>(mt, embW, degree, x);
    // gh = h0 @ Whh^T + bhh
    gemm_bt_mfma<<<dim3(48, 4), 256, 0, stream>>>(h0, 1024, Whh, 1024, 0, bhh, gh, 3072, 32, 8);

    // attn energies (bf16 MFMA) fused with tanh·v reduction -> scores
    fused_tanh_dot<<<dim3(64, 8), 256, 0, stream>>>(z_enc, azW, 2048, 1024,
                                                    hbz, 1024, azv, 0, scores_z);
    fused_tanh_dot<<<dim3(128, 8), 256, 0, stream>>>(u_enc, auW, 2048, 1024,
                                                     hbu, 1024, auv, 0, scores_u);

    // softmax over t + ctx; ctx written into GRU input x and proj input y
    k_softmax_ctx<<<dim3(64, 4), 256, 0, stream>>>(scores_z, z_enc, TZ, x, 1536, y, 0);
    k_softmax_ctx<<<dim3(64, 4), 256, 0, stream>>>(scores_u, u_enc, TU, x, 512, y, 1024);

    // GRU: gi = x @ Wih^T + bih  (K=2624 -> 82 k-steps, 4 chunks of 21)
    gemm_bt_mfma<<<dim3(48, 4), 256, 0, stream>>>(x, GIN, Wih, GIN, 0, bih, gi, 3072, 82, 21);
    k_gate<<<64, 256, 0, stream>>>(gi, gh, h0, gru, y, out_hid, out_gru);

    // copy2: tanh(z_enc @ c2W^T + c2b) · gru  ->  z_cs
    fused_tanh_dot<<<dim3(64, 8), 256, 0, stream>>>(z_enc, c2W, 1024, 0,
                                                    c2b, 0, gru, 1024, z_cs);

    // gen = [z_ctx|u_ctx|gru] @ proj_W^T + proj_b  (K=3072 -> 96 k-steps, 3 chunks)
    gemm_bt_mfma<<<dim3(125, 3), 256, 0, stream>>>(y, 3072, pW, 3072, 0, pb, gen, 8000, 96, 32);

    // sparse log-sum-exp path
    k_expw<<<64, 128, 0, stream>>>(z_cs, ew, mb);
    k_sparse<<<dim3(8, 64), 256, 0, stream>>>(sz, ew, mb, zcopy);

    // final softmax + combine
    k_final<<<64, 256, 0, stream>>>(gen, zcopy, out_proba);
}

// Round 3
// 864.418 us; speedup vs baseline: 1.6334x; 1.0656x over previous
//
#include <hip/hip_runtime.h>
#include <cmath>

#define B64 64
#define H 1024
#define E 512
#define DG 64
#define GIN 2624   // E + 2H + DG
#define TZ 128
#define TU 256
#define V 8000
#define VT 8128    // V + TZ
#define NC 16128   // V + VT

using bf16x8 = __attribute__((ext_vector_type(8))) short;
using f32x4  = __attribute__((ext_vector_type(4))) float;

// pack two fp32 -> two bf16 in one dword
__device__ inline unsigned pack2(float a, float b) {
    unsigned ua = __float_as_uint(a) + 0x8000u;
    unsigned ub = __float_as_uint(b) + 0x8000u;
    return __builtin_amdgcn_perm(ub, ua, 0x07060302u);  // lo16=hi(a), hi16=hi(b)
}
__device__ inline uint2 pack4(float4 v) {
    return make_uint2(pack2(v.x, v.y), pack2(v.z, v.w));
}

// async global->LDS, 16B per lane; lptr must be wave-uniform (HW adds lane*16)
__device__ inline void gl_lds16(const void* gptr, void* lptr) {
    __builtin_amdgcn_global_load_lds(
        (const __attribute__((address_space(1))) void*)gptr,
        (__attribute__((address_space(3))) void*)lptr, 16, 0, 0);
}

// dst[n*1024 + k] = bf16(src[n*ld + koff + k]); grid = N, block 256
__global__ void k_cvt(const float* __restrict__ src, int ld, int koff,
                      unsigned short* __restrict__ dst)
{
    int n = blockIdx.x, k4 = threadIdx.x * 4;
    float4 v = *(const float4*)(src + (size_t)n * ld + koff + k4);
    *(uint2*)(dst + (size_t)n * 1024 + k4) = pack4(v);
}

// ---------------------------------------------------------------------------
// Fused: out[row] += sum_col tanh( (A @ W^T)[row,col] + addv[b,col] ) * multv[b,col]
// A: (M,1024) bf16 row-major (row = t*64+b). W: (1024,1024) bf16 row-major.
// grid (M/128, 8), block 256. m97-style global_load_lds staging, BK=32.
// ---------------------------------------------------------------------------
__global__ __launch_bounds__(256) void fused_tanh_dot_bf(
    const unsigned short* __restrict__ A,
    const unsigned short* __restrict__ W,
    const float* __restrict__ addv, int add_stride,
    const float* __restrict__ multv, int mult_stride,
    float* __restrict__ outs)
{
    __shared__ unsigned short As[128 * 32];
    __shared__ unsigned short Bs[128 * 32];
    const int tid  = threadIdx.x;
    const int wave = tid >> 6, lane = tid & 63;
    const int wm = wave >> 1, wn = wave & 1;
    const int q = lane >> 4, l16 = lane & 15;
    const int m0 = blockIdx.x * 128;
    const int n0 = blockIdx.y * 128;
    const int lrow = lane >> 2;        // 0..15
    const int lk   = (lane & 3) * 8;   // short offset within row

    f32x4 acc[4][4];
#pragma unroll
    for (int i = 0; i < 4; ++i)
#pragma unroll
        for (int j = 0; j < 4; ++j) acc[i][j] = f32x4{0.f, 0.f, 0.f, 0.f};

    for (int kt = 0; kt < 32; ++kt) {
        const int k0 = kt * 32;
        __syncthreads();
#pragma unroll
        for (int j = 0; j < 2; ++j) {
            int r0 = (wave * 2 + j) * 16;   // wave-uniform 16-row group
            gl_lds16(A + (size_t)(m0 + r0 + lrow) * 1024 + k0 + lk, &As[r0 * 32]);
            gl_lds16(W + (size_t)(n0 + r0 + lrow) * 1024 + k0 + lk, &Bs[r0 * 32]);
        }
        __syncthreads();
        bf16x8 af[4], bfr[4];
#pragma unroll
        for (int t = 0; t < 4; ++t) af[t]  = *(bf16x8*)&As[(wm * 64 + t * 16 + l16) * 32 + q * 8];
#pragma unroll
        for (int t = 0; t < 4; ++t) bfr[t] = *(bf16x8*)&Bs[(wn * 64 + t * 16 + l16) * 32 + q * 8];
#pragma unroll
        for (int tm = 0; tm < 4; ++tm)
#pragma unroll
            for (int tn = 0; tn < 4; ++tn)
                acc[tm][tn] = __builtin_amdgcn_mfma_f32_16x16x32_bf16(
                    af[tm], bfr[tn], acc[tm][tn], 0, 0, 0);
    }

    // C row = m0 + wm*64 + tm*16 + q*4 + r ; col = n0 + wn*64 + tn*16 + l16
#pragma unroll
    for (int tm = 0; tm < 4; ++tm) {
#pragma unroll
        for (int r = 0; r < 4; ++r) {
            int R = m0 + wm * 64 + tm * 16 + q * 4 + r;
            int b = R & 63;
            float s = 0.f;
#pragma unroll
            for (int tn = 0; tn < 4; ++tn) {
                int col = n0 + wn * 64 + tn * 16 + l16;
                float e = acc[tm][tn][r] + addv[(size_t)b * add_stride + col];
                s += tanhf(e) * multv[(size_t)b * mult_stride + col];
            }
            s += __shfl_xor(s, 1);
            s += __shfl_xor(s, 2);
            s += __shfl_xor(s, 4);
            s += __shfl_xor(s, 8);
            if (l16 == 0) atomicAdd(&outs[R], s);
        }
    }
}

// ---------------------------------------------------------------------------
// C(64,N) += A(64,lda chunk) @ W(N,ldw)^T  via bf16 MFMA, K-split over grid.y.
// C must be zeroed. bias added by chunk 0. grid (N/64, nchunks), block 256.
// ---------------------------------------------------------------------------
__global__ __launch_bounds__(256) void gemm_bt_mfma(
    const float* __restrict__ A, int lda,
    const float* __restrict__ W, int ldw, int koff,
    const float* __restrict__ bias,
    float* __restrict__ C, int N,
    int ks_total, int ks_chunk)
{
    __shared__ short As[64][40];
    __shared__ short Bs[64][40];
    const int tid  = threadIdx.x;
    const int wave = tid >> 6, lane = tid & 63;
    const int wm = wave >> 1, wn = wave & 1;
    const int q = lane >> 4, l16 = lane & 15;
    const int n0 = blockIdx.x * 64;
    const int kb = blockIdx.y * ks_chunk;
    const int ke = min(kb + ks_chunk, ks_total);

    f32x4 acc[2][2];
#pragma unroll
    for (int i = 0; i < 2; ++i)
#pragma unroll
        for (int j = 0; j < 2; ++j) acc[i][j] = f32x4{0.f, 0.f, 0.f, 0.f};

    for (int ks = kb; ks < ke; ++ks) {
        const int k0 = ks * 32;
        __syncthreads();
#pragma unroll
        for (int i = 0; i < 2; ++i) {
            int slot = i * 256 + tid;
            int row  = slot >> 3;
            int kq   = (slot & 7) << 2;
            float4 a = *(const float4*)(A + (size_t)row * lda + k0 + kq);
            *(uint2*)&As[row][kq] = pack4(a);
            float4 w = *(const float4*)(W + (size_t)(n0 + row) * ldw + koff + k0 + kq);
            *(uint2*)&Bs[row][kq] = pack4(w);
        }
        __syncthreads();
        bf16x8 af[2], bfr[2];
#pragma unroll
        for (int t = 0; t < 2; ++t) af[t]  = *(bf16x8*)&As[wm * 32 + t * 16 + l16][q * 8];
#pragma unroll
        for (int t = 0; t < 2; ++t) bfr[t] = *(bf16x8*)&Bs[wn * 32 + t * 16 + l16][q * 8];
#pragma unroll
        for (int tm = 0; tm < 2; ++tm)
#pragma unroll
            for (int tn = 0; tn < 2; ++tn)
                acc[tm][tn] = __builtin_amdgcn_mfma_f32_16x16x32_bf16(
                    af[tm], bfr[tn], acc[tm][tn], 0, 0, 0);
    }

#pragma unroll
    for (int tm = 0; tm < 2; ++tm) {
#pragma unroll
        for (int r = 0; r < 4; ++r) {
            int b = wm * 32 + tm * 16 + q * 4 + r;
#pragma unroll
            for (int tn = 0; tn < 2; ++tn) {
                int n = n0 + wn * 32 + tn * 16 + l16;
                float v = acc[tm][tn][r];
                if (blockIdx.y == 0) v += bias[n];
                atomicAdd(&C[(size_t)b * N + n], v);
            }
        }
    }
}

// x[b] = [ emb_W[mt[b]] (512) | u_ctx (1024) | z_ctx (1024) | degree (64) ]
__global__ void k_gather(const int* __restrict__ mt, const float* __restrict__ embW,
                         const float* __restrict__ degree, float* __restrict__ x)
{
    int b = blockIdx.x, tid = threadIdx.x;   // block 128
    int m = mt[b];
    for (int k = tid; k < E; k += 128) x[(size_t)b * GIN + k] = embW[(size_t)m * E + k];
    if (tid < DG) x[(size_t)b * GIN + E + 2 * H + tid] = degree[b * DG + tid];
}

// softmax over t of scores[t*64+b], then ctx[b,h] = sum_t alpha[t]*enc[t,b,h]
__global__ __launch_bounds__(256) void k_softmax_ctx(
    const float* __restrict__ scores, const float* __restrict__ enc, int T,
    float* __restrict__ x, int xoff, float* __restrict__ y, int yoff)
{
    __shared__ float red[256];
    __shared__ float al[256];
    int b = blockIdx.x, hc = blockIdx.y, tid = threadIdx.x;
    float s = (tid < T) ? scores[tid * B64 + b] : -1e30f;
    red[tid] = s; __syncthreads();
    for (int off = 128; off > 0; off >>= 1) {
        if (tid < off) red[tid] = fmaxf(red[tid], red[tid + off]);
        __syncthreads();
    }
    float mx = red[0]; __syncthreads();
    float e = (tid < T) ? expf(s - mx) : 0.f;
    red[tid] = e; __syncthreads();
    for (int off = 128; off > 0; off >>= 1) {
        if (tid < off) red[tid] += red[tid + off];
        __syncthreads();
    }
    float inv = 1.f / red[0];
    al[tid] = e * inv;
    __syncthreads();
    int h = hc * 256 + tid;
    float acc = 0.f;
    for (int t = 0; t < T; ++t) acc += al[t] * enc[((size_t)t * B64 + b) * H + h];
    x[(size_t)b * GIN + xoff + h] = acc;
    y[(size_t)b * 3072 + yoff + h] = acc;
}

__global__ void k_gate(const float* __restrict__ gi, const float* __restrict__ gh,
                       const float* __restrict__ h0, float* __restrict__ gru,
                       float* __restrict__ y, float* __restrict__ out_hid,
                       float* __restrict__ out_gru)
{
    int b = blockIdx.x, tid = threadIdx.x;
    for (int j = tid; j < H; j += 256) {
        float ir = gi[(size_t)b * 3072 + j];
        float iz = gi[(size_t)b * 3072 + H + j];
        float in_ = gi[(size_t)b * 3072 + 2 * H + j];
        float hr = gh[(size_t)b * 3072 + j];
        float hz = gh[(size_t)b * 3072 + H + j];
        float hn = gh[(size_t)b * 3072 + 2 * H + j];
        float r = 1.f / (1.f + expf(-(ir + hr)));
        float z = 1.f / (1.f + expf(-(iz + hz)));
        float n = tanhf(in_ + r * hn);
        float h = h0[(size_t)b * H + j];
        float o = (1.f - z) * n + z * h;
        gru[(size_t)b * H + j] = o;
        y[(size_t)b * 3072 + 2 * H + j] = o;
        out_hid[(size_t)b * H + j] = o;
        out_gru[(size_t)b * H + j] = o;
    }
}

// m[b] = max_t z_cs[t*64+b]; ew[b,t] = exp(z_cs - m). grid 64, block 128.
__global__ void k_expw(const float* __restrict__ z_cs, float* __restrict__ ew,
                       float* __restrict__ mb)
{
    __shared__ float red[128];
    int b = blockIdx.x, t = threadIdx.x;
    float s = z_cs[t * B64 + b];
    red[t] = s; __syncthreads();
    for (int off = 64; off > 0; off >>= 1) {
        if (t < off) red[t] = fmaxf(red[t], red[t + off]);
        __syncthreads();
    }
    float m = red[0];
    ew[b * TZ + t] = expf(s - m);
    if (t == 0) mb[b] = m;
}

// zcopy[b,v] = log( sum_t ew[b,t]*sz[b,t,v] ) + mb[b]. grid (8,64), block 256.
__global__ __launch_bounds__(256) void k_sparse(
    const float* __restrict__ sz, const float* __restrict__ ew,
    const float* __restrict__ mb, float* __restrict__ zcopy)
{
    __shared__ float es[TZ];
    int c = blockIdx.x, b = blockIdx.y, tid = threadIdx.x;
    if (tid < TZ) es[tid] = ew[b * TZ + tid];
    __syncthreads();
    if (tid >= 254) return;
    int v4 = c * 254 + tid;               // 8 * 254 = 2032 = 8128/4, exact cover
    const float4* base = (const float4*)(sz + (size_t)b * TZ * VT);
    float4 acc = make_float4(0.f, 0.f, 0.f, 0.f);
    for (int t = 0; t < TZ; ++t) {
        float4 xv = base[(size_t)t * (VT / 4) + v4];
        float e = es[t];
        acc.x += e * xv.x; acc.y += e * xv.y; acc.z += e * xv.z; acc.w += e * xv.w;
    }
    float m = mb[b];
    int v = v4 * 4;
    zcopy[(size_t)b * VT + v + 0] = logf(acc.x) + m;
    zcopy[(size_t)b * VT + v + 1] = logf(acc.y) + m;
    zcopy[(size_t)b * VT + v + 2] = logf(acc.z) + m;
    zcopy[(size_t)b * VT + v + 3] = logf(acc.w) + m;
}

// final softmax over [gen(8000) | zcopy(8128)]; proba combine. grid 64, block 1024.
__global__ __launch_bounds__(1024) void k_final(
    const float* __restrict__ gen, const float* __restrict__ zcopy,
    float* __restrict__ proba)
{
    __shared__ float lg[NC];
    __shared__ float wred[16];
    int b = blockIdx.x, tid = threadIdx.x;
    int lane = tid & 63, wave = tid >> 6;
    for (int i = tid; i < V; i += 1024) lg[i] = gen[(size_t)b * V + i];
    for (int i = tid; i < VT; i += 1024) lg[V + i] = zcopy[(size_t)b * VT + i];
    __syncthreads();
    float mx = -1e30f;
    for (int i = tid; i < NC; i += 1024) mx = fmaxf(mx, lg[i]);
#pragma unroll
    for (int off = 32; off > 0; off >>= 1) mx = fmaxf(mx, __shfl_xor(mx, off));
    if (lane == 0) wred[wave] = mx;
    __syncthreads();
    mx = wred[0];
#pragma unroll
    for (int w = 1; w < 16; ++w) mx = fmaxf(mx, wred[w]);
    __syncthreads();
    float sm = 0.f;
    for (int i = tid; i < NC; i += 1024) sm += expf(lg[i] - mx);
#pragma unroll
    for (int off = 32; off > 0; off >>= 1) sm += __shfl_xor(sm, off);
    if (lane == 0) wred[wave] = sm;
    __syncthreads();
    float Z = 0.f;
#pragma unroll
    for (int w = 0; w < 16; ++w) Z += wred[w];
    float invZ = 1.f / Z;
    for (int v = tid; v < VT; v += 1024) {
        float p = expf(lg[V + v] - mx) * invZ;
        if (v < V) p += expf(lg[v] - mx) * invZ;
        proba[(size_t)b * VT + v] = p;
    }
}

extern "C" void kernel_launch(void* const* d_in, const int* in_sizes, int n_in,
                              void* d_out, int out_size, void* d_ws, size_t ws_size,
                              hipStream_t stream)
{
    const float* z_enc  = (const float*)d_in[0];
    const float* u_enc  = (const float*)d_in[1];
    const int*   mt     = (const int*)d_in[2];
    const float* degree = (const float*)d_in[3];
    const float* h0     = (const float*)d_in[4];
    const float* sz     = (const float*)d_in[5];
    const float* embW   = (const float*)d_in[6];
    const float* azW    = (const float*)d_in[7];
    const float* azb    = (const float*)d_in[8];
    const float* azv    = (const float*)d_in[9];
    const float* auW    = (const float*)d_in[10];
    const float* aub    = (const float*)d_in[11];
    const float* auv    = (const float*)d_in[12];
    const float* Wih    = (const float*)d_in[13];
    const float* Whh    = (const float*)d_in[14];
    const float* bih    = (const float*)d_in[15];
    const float* bhh    = (const float*)d_in[16];
    const float* pW     = (const float*)d_in[17];
    const float* pb     = (const float*)d_in[18];
    const float* c2W    = (const float*)d_in[19];
    const float* c2b    = (const float*)d_in[20];

    float* ws       = (float*)d_ws;
    // zeroed region (atomic accumulators), contiguous:
    float* scores_z = ws;               // 8192   (t*64+b)
    float* scores_u = ws + 8192;        // 16384
    float* z_cs     = ws + 24576;       // 8192
    float* hbz      = ws + 32768;       // 65536
    float* hbu      = ws + 98304;       // 65536
    float* gi       = ws + 163840;      // 196608 (64*3072)
    float* gh       = ws + 360448;      // 196608
    float* gen      = ws + 557056;      // 512000 (64*8000)
    // non-zeroed:
    float* x        = ws + 1069056;     // 64*2624
    float* y        = ws + 1236992;     // 64*3072
    float* gru      = ws + 1433600;     // 64*1024
    float* ew       = ws + 1499136;     // 64*128
    float* mb       = ws + 1507328;     // 64
    float* zcopy    = ws + 1507392;     // 64*8128
    // bf16 area (shorts)
    unsigned short* ubf   = (unsigned short*)(ws + 2027584);  // 16384*1024
    unsigned short* zbf   = ubf + (size_t)16384 * 1024;       // 8192*1024
    unsigned short* azWbf = zbf + (size_t)8192 * 1024;        // 1024*1024
    unsigned short* auWbf = azWbf + (size_t)1024 * 1024;
    unsigned short* c2Wbf = auWbf + (size_t)1024 * 1024;

    float* out_proba = (float*)d_out;
    float* out_hid   = out_proba + (size_t)B64 * VT;
    float* out_gru   = out_hid + (size_t)B64 * H;

    // zero all atomic accumulators in one shot
    hipMemsetAsync(ws, 0, 1069056 * sizeof(float), stream);

    // fp32 -> bf16 prepass (enc matrices + weight slices)
    k_cvt<<<16384, 256, 0, stream>>>(u_enc, 1024, 0, ubf);
    k_cvt<<<8192, 256, 0, stream>>>(z_enc, 1024, 0, zbf);
    k_cvt<<<1024, 256, 0, stream>>>(azW, 2048, 1024, azWbf);
    k_cvt<<<1024, 256, 0, stream>>>(auW, 2048, 1024, auWbf);
    k_cvt<<<1024, 256, 0, stream>>>(c2W, 1024, 0, c2Wbf);

    // hb[b,h] = hidden @ W[:, :H]^T + bias (per-batch half of attn energy)
    gemm_bt_mfma<<<dim3(16, 4), 256, 0, stream>>>(h0, 1024, azW, 2048, 0, azb, hbz, 1024, 32, 8);
    gemm_bt_mfma<<<dim3(16, 4), 256, 0, stream>>>(h0, 1024, auW, 2048, 0, aub, hbu, 1024, 32, 8);
    k_gather<<<64, 128, 0, stream>>>(mt, embW, degree, x);
    gemm_bt_mfma<<<dim3(48, 4), 256, 0, stream>>>(h0, 1024, Whh, 1024, 0, bhh, gh, 3072, 32, 8);

    // attn energies fused with tanh·v reduction -> scores
    fused_tanh_dot_bf<<<dim3(64, 8), 256, 0, stream>>>(zbf, azWbf, hbz, 1024, azv, 0, scores_z);
    fused_tanh_dot_bf<<<dim3(128, 8), 256, 0, stream>>>(ubf, auWbf, hbu, 1024, auv, 0, scores_u);

    // softmax over t + ctx; ctx written into GRU input x and proj input y
    k_softmax_ctx<<<dim3(64, 4), 256, 0, stream>>>(scores_z, z_enc, TZ, x, 1536, y, 0);
    k_softmax_ctx<<<dim3(64, 4), 256, 0, stream>>>(scores_u, u_enc, TU, x, 512, y, 1024);

    // GRU: gi = x @ Wih^T + bih  (K=2624 -> 82 k-steps, 4 chunks of 21)
    gemm_bt_mfma<<<dim3(48, 4), 256, 0, stream>>>(x, GIN, Wih, GIN, 0, bih, gi, 3072, 82, 21);
    k_gate<<<64, 256, 0, stream>>>(gi, gh, h0, gru, y, out_hid, out_gru);

    // copy2: tanh(z_enc @ c2W^T + c2b) · gru  ->  z_cs
    fused_tanh_dot_bf<<<dim3(64, 8), 256, 0, stream>>>(zbf, c2Wbf, c2b, 0, gru, 1024, z_cs);

    // gen = [z_ctx|u_ctx|gru] @ proj_W^T + proj_b  (K=3072 -> 96 k-steps, 3 chunks)
    gemm_bt_mfma<<<dim3(125, 3), 256, 0, stream>>>(y, 3072, pW, 3072, 0, pb, gen, 8000, 96, 32);

    // sparse log-sum-exp path
    k_expw<<<64, 128, 0, stream>>>(z_cs, ew, mb);
    k_sparse<<<dim3(8, 64), 256, 0, stream>>>(sz, ew, mb, zcopy);

    // final softmax + combine
    k_final<<<64, 1024, 0, stream>>>(gen, zcopy, out_proba);
}

// Round 4
// 812.358 us; speedup vs baseline: 1.7381x; 1.0641x over previous
//
#include <hip/hip_runtime.h>
#include <cmath>

#define B64 64
#define H 1024
#define E 512
#define DG 64
#define GIN 2624   // E + 2H + DG
#define TZ 128
#define TU 256
#define V 8000
#define VT 8128    // V + TZ
#define NC 16128   // V + VT

using bf16x8 = __attribute__((ext_vector_type(8))) short;
using f32x4  = __attribute__((ext_vector_type(4))) float;

// pack two fp32 -> two bf16 in one dword
__device__ inline unsigned pack2(float a, float b) {
    unsigned ua = __float_as_uint(a) + 0x8000u;
    unsigned ub = __float_as_uint(b) + 0x8000u;
    return __builtin_amdgcn_perm(ub, ua, 0x07060302u);  // lo16=hi(a), hi16=hi(b)
}
__device__ inline uint2 pack4(float4 v) {
    return make_uint2(pack2(v.x, v.y), pack2(v.z, v.w));
}

// fast tanh via hw exp: tanh(x) = 1 - 2/(e^{2x}+1); exact at +-inf
__device__ inline float fast_tanh(float x) {
    float e = __expf(2.f * x);
    return 1.f - 2.f / (e + 1.f);
}
__device__ inline float fast_sig(float x) {
    return 1.f / (1.f + __expf(-x));
}

// async global->LDS, 16B per lane; lptr must be wave-uniform (HW adds lane*16)
__device__ inline void gl_lds16(const void* gptr, void* lptr) {
    __builtin_amdgcn_global_load_lds(
        (const __attribute__((address_space(1))) void*)gptr,
        (__attribute__((address_space(3))) void*)lptr, 16, 0, 0);
}

// one-shot fp32->bf16 prepass: u_enc | z_enc | azW[:,1024:] | auW[:,1024:] | c2W
// grid 27648, block 256
__global__ void k_cvt_all(const float* __restrict__ u_enc, const float* __restrict__ z_enc,
                          const float* __restrict__ azW, const float* __restrict__ auW,
                          const float* __restrict__ c2W,
                          unsigned short* __restrict__ ubf, unsigned short* __restrict__ zbf,
                          unsigned short* __restrict__ azWbf, unsigned short* __restrict__ auWbf,
                          unsigned short* __restrict__ c2Wbf)
{
    int n = blockIdx.x, k4 = threadIdx.x * 4;
    const float* src; unsigned short* dst; int ld, koff, r;
    if (n < 16384)      { src = u_enc; dst = ubf;   ld = 1024; koff = 0;    r = n; }
    else if (n < 24576) { src = z_enc; dst = zbf;   ld = 1024; koff = 0;    r = n - 16384; }
    else if (n < 25600) { src = azW;   dst = azWbf; ld = 2048; koff = 1024; r = n - 24576; }
    else if (n < 26624) { src = auW;   dst = auWbf; ld = 2048; koff = 1024; r = n - 25600; }
    else                { src = c2W;   dst = c2Wbf; ld = 1024; koff = 0;    r = n - 26624; }
    float4 v = *(const float4*)(src + (size_t)r * ld + koff + k4);
    *(uint2*)(dst + (size_t)r * 1024 + k4) = pack4(v);
}

// ---------------------------------------------------------------------------
// Fused: out[row] += sum_col tanh( (A @ W^T)[row,col] + addv[b,col] ) * multv[b,col]
// A: (M,1024) bf16 row-major (row = t*64+b). W: (1024,1024) bf16 row-major.
// grid (M/128, 8), block 256.
// ---------------------------------------------------------------------------
__global__ __launch_bounds__(256) void fused_tanh_dot_bf(
    const unsigned short* __restrict__ A,
    const unsigned short* __restrict__ W,
    const float* __restrict__ addv, int add_stride,
    const float* __restrict__ multv, int mult_stride,
    float* __restrict__ outs)
{
    __shared__ unsigned short As[128 * 32];
    __shared__ unsigned short Bs[128 * 32];
    const int tid  = threadIdx.x;
    const int wave = tid >> 6, lane = tid & 63;
    const int wm = wave >> 1, wn = wave & 1;
    const int q = lane >> 4, l16 = lane & 15;
    const int m0 = blockIdx.x * 128;
    const int n0 = blockIdx.y * 128;
    const int lrow = lane >> 2;
    const int lk   = (lane & 3) * 8;

    f32x4 acc[4][4];
#pragma unroll
    for (int i = 0; i < 4; ++i)
#pragma unroll
        for (int j = 0; j < 4; ++j) acc[i][j] = f32x4{0.f, 0.f, 0.f, 0.f};

    for (int kt = 0; kt < 32; ++kt) {
        const int k0 = kt * 32;
        __syncthreads();
#pragma unroll
        for (int j = 0; j < 2; ++j) {
            int r0 = (wave * 2 + j) * 16;
            gl_lds16(A + (size_t)(m0 + r0 + lrow) * 1024 + k0 + lk, &As[r0 * 32]);
            gl_lds16(W + (size_t)(n0 + r0 + lrow) * 1024 + k0 + lk, &Bs[r0 * 32]);
        }
        __syncthreads();
        bf16x8 af[4], bfr[4];
#pragma unroll
        for (int t = 0; t < 4; ++t) af[t]  = *(bf16x8*)&As[(wm * 64 + t * 16 + l16) * 32 + q * 8];
#pragma unroll
        for (int t = 0; t < 4; ++t) bfr[t] = *(bf16x8*)&Bs[(wn * 64 + t * 16 + l16) * 32 + q * 8];
#pragma unroll
        for (int tm = 0; tm < 4; ++tm)
#pragma unroll
            for (int tn = 0; tn < 4; ++tn)
                acc[tm][tn] = __builtin_amdgcn_mfma_f32_16x16x32_bf16(
                    af[tm], bfr[tn], acc[tm][tn], 0, 0, 0);
    }

#pragma unroll
    for (int tm = 0; tm < 4; ++tm) {
#pragma unroll
        for (int r = 0; r < 4; ++r) {
            int R = m0 + wm * 64 + tm * 16 + q * 4 + r;
            int b = R & 63;
            float s = 0.f;
#pragma unroll
            for (int tn = 0; tn < 4; ++tn) {
                int col = n0 + wn * 64 + tn * 16 + l16;
                float e = acc[tm][tn][r] + addv[(size_t)b * add_stride + col];
                s += fast_tanh(e) * multv[(size_t)b * mult_stride + col];
            }
            s += __shfl_xor(s, 1);
            s += __shfl_xor(s, 2);
            s += __shfl_xor(s, 4);
            s += __shfl_xor(s, 8);
            if (l16 == 0) atomicAdd(&outs[R], s);
        }
    }
}

// ---------------------------------------------------------------------------
// Combined z-side kernel: grid (64,16), block 256.
//  y<8 : scores_z epilogue  (add=hbz stride 1024, mult=azv)  -> atomicAdd
//  y>=8: tz = tanh(z_enc @ c2W^T + c2b)  materialized fp32
// ---------------------------------------------------------------------------
__global__ __launch_bounds__(256) void ftd_z_combo(
    const unsigned short* __restrict__ A,
    const unsigned short* __restrict__ Wz,
    const float* __restrict__ hbz, const float* __restrict__ azv,
    float* __restrict__ scores,
    const unsigned short* __restrict__ Wc,
    const float* __restrict__ c2b,
    float* __restrict__ tz)
{
    __shared__ unsigned short As[128 * 32];
    __shared__ unsigned short Bs[128 * 32];
    const int tid  = threadIdx.x;
    const int wave = tid >> 6, lane = tid & 63;
    const int wm = wave >> 1, wn = wave & 1;
    const int q = lane >> 4, l16 = lane & 15;
    const int m0 = blockIdx.x * 128;
    const bool isz = blockIdx.y < 8;
    const int n0 = (isz ? blockIdx.y : blockIdx.y - 8) * 128;
    const unsigned short* W = isz ? Wz : Wc;
    const int lrow = lane >> 2;
    const int lk   = (lane & 3) * 8;

    f32x4 acc[4][4];
#pragma unroll
    for (int i = 0; i < 4; ++i)
#pragma unroll
        for (int j = 0; j < 4; ++j) acc[i][j] = f32x4{0.f, 0.f, 0.f, 0.f};

    for (int kt = 0; kt < 32; ++kt) {
        const int k0 = kt * 32;
        __syncthreads();
#pragma unroll
        for (int j = 0; j < 2; ++j) {
            int r0 = (wave * 2 + j) * 16;
            gl_lds16(A + (size_t)(m0 + r0 + lrow) * 1024 + k0 + lk, &As[r0 * 32]);
            gl_lds16(W + (size_t)(n0 + r0 + lrow) * 1024 + k0 + lk, &Bs[r0 * 32]);
        }
        __syncthreads();
        bf16x8 af[4], bfr[4];
#pragma unroll
        for (int t = 0; t < 4; ++t) af[t]  = *(bf16x8*)&As[(wm * 64 + t * 16 + l16) * 32 + q * 8];
#pragma unroll
        for (int t = 0; t < 4; ++t) bfr[t] = *(bf16x8*)&Bs[(wn * 64 + t * 16 + l16) * 32 + q * 8];
#pragma unroll
        for (int tm = 0; tm < 4; ++tm)
#pragma unroll
            for (int tn = 0; tn < 4; ++tn)
                acc[tm][tn] = __builtin_amdgcn_mfma_f32_16x16x32_bf16(
                    af[tm], bfr[tn], acc[tm][tn], 0, 0, 0);
    }

    if (isz) {
#pragma unroll
        for (int tm = 0; tm < 4; ++tm) {
#pragma unroll
            for (int r = 0; r < 4; ++r) {
                int R = m0 + wm * 64 + tm * 16 + q * 4 + r;
                int b = R & 63;
                float s = 0.f;
#pragma unroll
                for (int tn = 0; tn < 4; ++tn) {
                    int col = n0 + wn * 64 + tn * 16 + l16;
                    float e = acc[tm][tn][r] + hbz[(size_t)b * 1024 + col];
                    s += fast_tanh(e) * azv[col];
                }
                s += __shfl_xor(s, 1);
                s += __shfl_xor(s, 2);
                s += __shfl_xor(s, 4);
                s += __shfl_xor(s, 8);
                if (l16 == 0) atomicAdd(&scores[R], s);
            }
        }
    } else {
#pragma unroll
        for (int tm = 0; tm < 4; ++tm) {
#pragma unroll
            for (int r = 0; r < 4; ++r) {
                int R = m0 + wm * 64 + tm * 16 + q * 4 + r;
#pragma unroll
                for (int tn = 0; tn < 4; ++tn) {
                    int col = n0 + wn * 64 + tn * 16 + l16;
                    tz[(size_t)R * 1024 + col] = fast_tanh(acc[tm][tn][r] + c2b[col]);
                }
            }
        }
    }
}

// ---------------------------------------------------------------------------
// C(64,N) += A(64,lda chunk) @ W(N,ldw)^T  via bf16 MFMA, K-split over grid.y.
// ---------------------------------------------------------------------------
__global__ __launch_bounds__(256) void gemm_bt_mfma(
    const float* __restrict__ A, int lda,
    const float* __restrict__ W, int ldw, int koff,
    const float* __restrict__ bias,
    float* __restrict__ C, int N,
    int ks_total, int ks_chunk)
{
    __shared__ short As[64][40];
    __shared__ short Bs[64][40];
    const int tid  = threadIdx.x;
    const int wave = tid >> 6, lane = tid & 63;
    const int wm = wave >> 1, wn = wave & 1;
    const int q = lane >> 4, l16 = lane & 15;
    const int n0 = blockIdx.x * 64;
    const int kb = blockIdx.y * ks_chunk;
    const int ke = min(kb + ks_chunk, ks_total);

    f32x4 acc[2][2];
#pragma unroll
    for (int i = 0; i < 2; ++i)
#pragma unroll
        for (int j = 0; j < 2; ++j) acc[i][j] = f32x4{0.f, 0.f, 0.f, 0.f};

    for (int ks = kb; ks < ke; ++ks) {
        const int k0 = ks * 32;
        __syncthreads();
#pragma unroll
        for (int i = 0; i < 2; ++i) {
            int slot = i * 256 + tid;
            int row  = slot >> 3;
            int kq   = (slot & 7) << 2;
            float4 a = *(const float4*)(A + (size_t)row * lda + k0 + kq);
            *(uint2*)&As[row][kq] = pack4(a);
            float4 w = *(const float4*)(W + (size_t)(n0 + row) * ldw + koff + k0 + kq);
            *(uint2*)&Bs[row][kq] = pack4(w);
        }
        __syncthreads();
        bf16x8 af[2], bfr[2];
#pragma unroll
        for (int t = 0; t < 2; ++t) af[t]  = *(bf16x8*)&As[wm * 32 + t * 16 + l16][q * 8];
#pragma unroll
        for (int t = 0; t < 2; ++t) bfr[t] = *(bf16x8*)&Bs[wn * 32 + t * 16 + l16][q * 8];
#pragma unroll
        for (int tm = 0; tm < 2; ++tm)
#pragma unroll
            for (int tn = 0; tn < 2; ++tn)
                acc[tm][tn] = __builtin_amdgcn_mfma_f32_16x16x32_bf16(
                    af[tm], bfr[tn], acc[tm][tn], 0, 0, 0);
    }

#pragma unroll
    for (int tm = 0; tm < 2; ++tm) {
#pragma unroll
        for (int r = 0; r < 4; ++r) {
            int b = wm * 32 + tm * 16 + q * 4 + r;
#pragma unroll
            for (int tn = 0; tn < 2; ++tn) {
                int n = n0 + wn * 32 + tn * 16 + l16;
                float v = acc[tm][tn][r];
                if (blockIdx.y == 0) v += bias[n];
                atomicAdd(&C[(size_t)b * N + n], v);
            }
        }
    }
}

// x[b] = [ emb_W[mt[b]] (512) | u_ctx (1024) | z_ctx (1024) | degree (64) ]
__global__ void k_gather(const int* __restrict__ mt, const float* __restrict__ embW,
                         const float* __restrict__ degree, float* __restrict__ x)
{
    int b = blockIdx.x, tid = threadIdx.x;   // block 128
    int m = mt[b];
    for (int k = tid; k < E; k += 128) x[(size_t)b * GIN + k] = embW[(size_t)m * E + k];
    if (tid < DG) x[(size_t)b * GIN + E + 2 * H + tid] = degree[b * DG + tid];
}

// softmax over t of scores[t*64+b], ctx from bf16 enc. grid (64,2), block 256.
__global__ __launch_bounds__(256) void k_softmax_ctx_bf(
    const float* __restrict__ scores, const unsigned short* __restrict__ encbf, int T,
    float* __restrict__ x, int xoff, float* __restrict__ y, int yoff)
{
    __shared__ float red[256];
    __shared__ float al[256];
    int b = blockIdx.x, hc = blockIdx.y, tid = threadIdx.x;
    float s = (tid < T) ? scores[tid * B64 + b] : -1e30f;
    red[tid] = s; __syncthreads();
    for (int off = 128; off > 0; off >>= 1) {
        if (tid < off) red[tid] = fmaxf(red[tid], red[tid + off]);
        __syncthreads();
    }
    float mx = red[0]; __syncthreads();
    float e = (tid < T) ? __expf(s - mx) : 0.f;
    red[tid] = e; __syncthreads();
    for (int off = 128; off > 0; off >>= 1) {
        if (tid < off) red[tid] += red[tid + off];
        __syncthreads();
    }
    float inv = 1.f / red[0];
    al[tid] = e * inv;
    __syncthreads();
    int h = hc * 512 + tid * 2;
    float a0 = 0.f, a1 = 0.f;
    for (int t = 0; t < T; ++t) {
        unsigned u = *(const unsigned*)(encbf + ((size_t)t * B64 + b) * 1024 + h);
        float w = al[t];
        a0 += w * __uint_as_float(u << 16);
        a1 += w * __uint_as_float(u & 0xffff0000u);
    }
    x[(size_t)b * GIN + xoff + h]     = a0;
    x[(size_t)b * GIN + xoff + h + 1] = a1;
    y[(size_t)b * 3072 + yoff + h]     = a0;
    y[(size_t)b * 3072 + yoff + h + 1] = a1;
}

__global__ void k_gate(const float* __restrict__ gi, const float* __restrict__ gh,
                       const float* __restrict__ h0, float* __restrict__ gru,
                       float* __restrict__ y, float* __restrict__ out_hid,
                       float* __restrict__ out_gru)
{
    int b = blockIdx.x, tid = threadIdx.x;
    for (int j = tid; j < H; j += 256) {
        float ir = gi[(size_t)b * 3072 + j];
        float iz = gi[(size_t)b * 3072 + H + j];
        float in_ = gi[(size_t)b * 3072 + 2 * H + j];
        float hr = gh[(size_t)b * 3072 + j];
        float hz = gh[(size_t)b * 3072 + H + j];
        float hn = gh[(size_t)b * 3072 + 2 * H + j];
        float r = fast_sig(ir + hr);
        float z = fast_sig(iz + hz);
        float n = fast_tanh(in_ + r * hn);
        float h = h0[(size_t)b * H + j];
        float o = (1.f - z) * n + z * h;
        gru[(size_t)b * H + j] = o;
        y[(size_t)b * 3072 + 2 * H + j] = o;
        out_hid[(size_t)b * H + j] = o;
        out_gru[(size_t)b * H + j] = o;
    }
}

// z_cs[t,b] = dot(tz[t*64+b,:], gru[b,:]); then m=max_t, ew=exp(s-m).
// grid 64 (one block per b), block 512 (8 waves).
__global__ __launch_bounds__(512) void k_zcs_expw(
    const float* __restrict__ tz, const float* __restrict__ gru,
    float* __restrict__ ew, float* __restrict__ mb)
{
    __shared__ float g[1024];
    __shared__ float srow[TZ];
    __shared__ float red[64];
    int b = blockIdx.x, tid = threadIdx.x;
    int wave = tid >> 6, lane = tid & 63;
    for (int i = tid; i < 1024; i += 512) g[i] = gru[(size_t)b * 1024 + i];
    __syncthreads();
    float gr[16];
#pragma unroll
    for (int j = 0; j < 16; ++j) gr[j] = g[lane * 16 + j];
    for (int t = wave; t < TZ; t += 8) {
        const float* row = tz + ((size_t)t * B64 + b) * 1024 + lane * 16;
        float s = 0.f;
#pragma unroll
        for (int c = 0; c < 4; ++c) {
            float4 v = *(const float4*)(row + c * 4);
            s += v.x * gr[c * 4 + 0] + v.y * gr[c * 4 + 1]
               + v.z * gr[c * 4 + 2] + v.w * gr[c * 4 + 3];
        }
#pragma unroll
        for (int off = 32; off > 0; off >>= 1) s += __shfl_xor(s, off);
        if (lane == 0) srow[t] = s;
    }
    __syncthreads();
    if (tid < 64) red[tid] = fmaxf(srow[tid], srow[tid + 64]);
    __syncthreads();
    if (tid < 64) {
        float m = red[tid];
#pragma unroll
        for (int off = 32; off > 0; off >>= 1) m = fmaxf(m, __shfl_xor(m, off));
        red[tid] = m;
    }
    __syncthreads();
    float m = red[0];
    if (tid < TZ) ew[b * TZ + tid] = __expf(srow[tid] - m);
    if (tid == 0) mb[b] = m;
}

// zcopy[b,v] = log( sum_t ew[b,t]*sz[b,t,v] ) + mb[b]. grid (8,64), block 256.
__global__ __launch_bounds__(256) void k_sparse(
    const float* __restrict__ sz, const float* __restrict__ ew,
    const float* __restrict__ mb, float* __restrict__ zcopy)
{
    __shared__ float es[TZ];
    int c = blockIdx.x, b = blockIdx.y, tid = threadIdx.x;
    if (tid < TZ) es[tid] = ew[b * TZ + tid];
    __syncthreads();
    if (tid >= 254) return;
    int v4 = c * 254 + tid;               // 8 * 254 = 2032 = 8128/4, exact cover
    const float4* base = (const float4*)(sz + (size_t)b * TZ * VT);
    float4 acc = make_float4(0.f, 0.f, 0.f, 0.f);
    for (int t = 0; t < TZ; ++t) {
        float4 xv = base[(size_t)t * (VT / 4) + v4];
        float e = es[t];
        acc.x += e * xv.x; acc.y += e * xv.y; acc.z += e * xv.z; acc.w += e * xv.w;
    }
    float m = mb[b];
    int v = v4 * 4;
    zcopy[(size_t)b * VT + v + 0] = __logf(acc.x) + m;
    zcopy[(size_t)b * VT + v + 1] = __logf(acc.y) + m;
    zcopy[(size_t)b * VT + v + 2] = __logf(acc.z) + m;
    zcopy[(size_t)b * VT + v + 3] = __logf(acc.w) + m;
}

// final softmax over [gen(8000) | zcopy(8128)]; proba combine. grid 64, block 1024.
__global__ __launch_bounds__(1024) void k_final(
    const float* __restrict__ gen, const float* __restrict__ zcopy,
    float* __restrict__ proba)
{
    __shared__ float lg[NC];
    __shared__ float wred[16];
    int b = blockIdx.x, tid = threadIdx.x;
    int lane = tid & 63, wave = tid >> 6;
    for (int i = tid; i < V; i += 1024) lg[i] = gen[(size_t)b * V + i];
    for (int i = tid; i < VT; i += 1024) lg[V + i] = zcopy[(size_t)b * VT + i];
    __syncthreads();
    float mx = -1e30f;
    for (int i = tid; i < NC; i += 1024) mx = fmaxf(mx, lg[i]);
#pragma unroll
    for (int off = 32; off > 0; off >>= 1) mx = fmaxf(mx, __shfl_xor(mx, off));
    if (lane == 0) wred[wave] = mx;
    __syncthreads();
    mx = wred[0];
#pragma unroll
    for (int w = 1; w < 16; ++w) mx = fmaxf(mx, wred[w]);
    __syncthreads();
    float sm = 0.f;
    for (int i = tid; i < NC; i += 1024) sm += __expf(lg[i] - mx);
#pragma unroll
    for (int off = 32; off > 0; off >>= 1) sm += __shfl_xor(sm, off);
    if (lane == 0) wred[wave] = sm;
    __syncthreads();
    float Z = 0.f;
#pragma unroll
    for (int w = 0; w < 16; ++w) Z += wred[w];
    float invZ = 1.f / Z;
    for (int v = tid; v < VT; v += 1024) {
        float p = __expf(lg[V + v] - mx) * invZ;
        if (v < V) p += __expf(lg[v] - mx) * invZ;
        proba[(size_t)b * VT + v] = p;
    }
}

extern "C" void kernel_launch(void* const* d_in, const int* in_sizes, int n_in,
                              void* d_out, int out_size, void* d_ws, size_t ws_size,
                              hipStream_t stream)
{
    const float* z_enc  = (const float*)d_in[0];
    const float* u_enc  = (const float*)d_in[1];
    const int*   mt     = (const int*)d_in[2];
    const float* degree = (const float*)d_in[3];
    const float* h0     = (const float*)d_in[4];
    const float* sz     = (const float*)d_in[5];
    const float* embW   = (const float*)d_in[6];
    const float* azW    = (const float*)d_in[7];
    const float* azb    = (const float*)d_in[8];
    const float* azv    = (const float*)d_in[9];
    const float* auW    = (const float*)d_in[10];
    const float* aub    = (const float*)d_in[11];
    const float* auv    = (const float*)d_in[12];
    const float* Wih    = (const float*)d_in[13];
    const float* Whh    = (const float*)d_in[14];
    const float* bih    = (const float*)d_in[15];
    const float* bhh    = (const float*)d_in[16];
    const float* pW     = (const float*)d_in[17];
    const float* pb     = (const float*)d_in[18];
    const float* c2W    = (const float*)d_in[19];
    const float* c2b    = (const float*)d_in[20];

    float* ws       = (float*)d_ws;
    // zeroed region (atomic accumulators), contiguous:
    float* scores_z = ws;               // 8192   (t*64+b)
    float* scores_u = ws + 8192;        // 16384
    float* hbz      = ws + 32768;       // 65536
    float* hbu      = ws + 98304;       // 65536
    float* gi       = ws + 163840;      // 196608 (64*3072)
    float* gh       = ws + 360448;      // 196608
    float* gen      = ws + 557056;      // 512000 (64*8000)
    // non-zeroed:
    float* x        = ws + 1069056;     // 64*2624
    float* y        = ws + 1236992;     // 64*3072
    float* gru      = ws + 1433600;     // 64*1024
    float* ew       = ws + 1499136;     // 64*128
    float* mb       = ws + 1507328;     // 64
    float* zcopy    = ws + 1507392;     // 64*8128
    float* tz       = ws + 2027584;     // 8192*1024 fp32 tanh-energy
    // bf16 area (shorts)
    unsigned short* ubf   = (unsigned short*)(ws + 2027584 + 8388608);
    unsigned short* zbf   = ubf + (size_t)16384 * 1024;
    unsigned short* azWbf = zbf + (size_t)8192 * 1024;
    unsigned short* auWbf = azWbf + (size_t)1024 * 1024;
    unsigned short* c2Wbf = auWbf + (size_t)1024 * 1024;

    float* out_proba = (float*)d_out;
    float* out_hid   = out_proba + (size_t)B64 * VT;
    float* out_gru   = out_hid + (size_t)B64 * H;

    // zero all atomic accumulators in one shot
    hipMemsetAsync(ws, 0, 1069056 * sizeof(float), stream);

    // fp32 -> bf16 prepass (one launch)
    k_cvt_all<<<27648, 256, 0, stream>>>(u_enc, z_enc, azW, auW, c2W,
                                         ubf, zbf, azWbf, auWbf, c2Wbf);

    // hb[b,h] = hidden @ W[:, :H]^T + bias (per-batch half of attn energy)
    gemm_bt_mfma<<<dim3(16, 4), 256, 0, stream>>>(h0, 1024, azW, 2048, 0, azb, hbz, 1024, 32, 8);
    gemm_bt_mfma<<<dim3(16, 4), 256, 0, stream>>>(h0, 1024, auW, 2048, 0, aub, hbu, 1024, 32, 8);
    k_gather<<<64, 128, 0, stream>>>(mt, embW, degree, x);
    gemm_bt_mfma<<<dim3(48, 4), 256, 0, stream>>>(h0, 1024, Whh, 1024, 0, bhh, gh, 3072, 32, 8);

    // z-side: scores_z (y<8) + tz materialization (y>=8) in one launch
    ftd_z_combo<<<dim3(64, 16), 256, 0, stream>>>(zbf, azWbf, hbz, azv, scores_z,
                                                  c2Wbf, c2b, tz);
    // u-side attn energy fused with tanh·v reduction -> scores_u
    fused_tanh_dot_bf<<<dim3(128, 8), 256, 0, stream>>>(ubf, auWbf, hbu, 1024, auv, 0, scores_u);

    // softmax over t + ctx (bf16 enc reads)
    k_softmax_ctx_bf<<<dim3(64, 2), 256, 0, stream>>>(scores_z, zbf, TZ, x, 1536, y, 0);
    k_softmax_ctx_bf<<<dim3(64, 2), 256, 0, stream>>>(scores_u, ubf, TU, x, 512, y, 1024);

    // GRU: gi = x @ Wih^T + bih  (K=2624 -> 82 k-steps, 4 chunks of 21)
    gemm_bt_mfma<<<dim3(48, 4), 256, 0, stream>>>(x, GIN, Wih, GIN, 0, bih, gi, 3072, 82, 21);
    k_gate<<<64, 256, 0, stream>>>(gi, gh, h0, gru, y, out_hid, out_gru);

    // z_cs = tz · gru, then max/exp (fused)
    k_zcs_expw<<<64, 512, 0, stream>>>(tz, gru, ew, mb);

    // gen = [z_ctx|u_ctx|gru] @ proj_W^T + proj_b  (K=3072 -> 96 k-steps, 3 chunks)
    gemm_bt_mfma<<<dim3(125, 3), 256, 0, stream>>>(y, 3072, pW, 3072, 0, pb, gen, 8000, 96, 32);

    // sparse log-sum-exp path
    k_sparse<<<dim3(8, 64), 256, 0, stream>>>(sz, ew, mb, zcopy);

    // final softmax + combine
    k_final<<<64, 1024, 0, stream>>>(gen, zcopy, out_proba);
}